// Round 2
// baseline (221.107 us; speedup 1.0000x reference)
//
#include <hip/hip_runtime.h>
#include <stdint.h>

#define N_ 8192
#define D_ 1024
// logit = dot(imn,capn)/T; fp8 operands pre-scaled by 16 -> acc = 256*dot
#define EPILOGUE_SCALE (10.0f / 256.0f)
#define ENC_SCALE 16.0f
#define SLAB 262144  // bytes of one K-slab: 512 tiles x 512B fragments

typedef float f32x4 __attribute__((ext_vector_type(4)));

// async global->LDS, 16B per lane, LDS dest = wave-uniform base + lane*16
#define GLD16(gsrc, ldst)                                                    \
  __builtin_amdgcn_global_load_lds(                                          \
      (const __attribute__((address_space(1))) unsigned int*)(gsrc),         \
      (__attribute__((address_space(3))) unsigned int*)(ldst), 16, 0, 0)

// K=32 swizzled fragment layout (both operands), 8 MB each [R3/R5/R10-proven]:
//   byte addr = s*262144 + tile*512 + fl*8 + h*4
//   a wave's fragment (tile, s) is 64 lanes x 8B = 512B contiguous.

// Kernel 1 [unchanged — R2 is gemm-only for attribution]: normalize + fp8
// encode + fragment-order stores. 512 blocks x 16 waves.
__global__ __launch_bounds__(1024) void normalize_k(
    const float* __restrict__ im, const float* __restrict__ cap,
    unsigned int* __restrict__ imn, unsigned int* __restrict__ capn,
    float* __restrict__ diag, float* __restrict__ sums /* rowsum|colsum */) {
  __shared__ unsigned int ldsA[16 * 257];
  __shared__ unsigned int ldsB[16 * 257];
  const int til = blockIdx.x;
  const int t = threadIdx.x;
  if (til < 4) ((float4*)sums)[til * 1024 + t] = (float4){0.f, 0.f, 0.f, 0.f};

  const int r = t >> 6, j = t & 63;   // wave r = row r of tile; lane j
  const int row = til * 16 + r;
  const float4* __restrict__ aR = (const float4*)(im + (size_t)row * D_);
  const float4* __restrict__ bR = (const float4*)(cap + (size_t)row * D_);

  float4 a0 = aR[j], a1 = aR[j + 64], a2 = aR[j + 128], a3 = aR[j + 192];
  float4 b0 = bR[j], b1 = bR[j + 64], b2 = bR[j + 128], b3 = bR[j + 192];

  float ssa = a0.x * a0.x + a0.y * a0.y + a0.z * a0.z + a0.w * a0.w
            + a1.x * a1.x + a1.y * a1.y + a1.z * a1.z + a1.w * a1.w
            + a2.x * a2.x + a2.y * a2.y + a2.z * a2.z + a2.w * a2.w
            + a3.x * a3.x + a3.y * a3.y + a3.z * a3.z + a3.w * a3.w;
  float ssb = b0.x * b0.x + b0.y * b0.y + b0.z * b0.z + b0.w * b0.w
            + b1.x * b1.x + b1.y * b1.y + b1.z * b1.z + b1.w * b1.w
            + b2.x * b2.x + b2.y * b2.y + b2.z * b2.z + b2.w * b2.w
            + b3.x * b3.x + b3.y * b3.y + b3.z * b3.z + b3.w * b3.w;
  float dt  = a0.x * b0.x + a0.y * b0.y + a0.z * b0.z + a0.w * b0.w
            + a1.x * b1.x + a1.y * b1.y + a1.z * b1.z + a1.w * b1.w
            + a2.x * b2.x + a2.y * b2.y + a2.z * b2.z + a2.w * b2.w
            + a3.x * b3.x + a3.y * b3.y + a3.z * b3.z + a3.w * b3.w;
#pragma unroll
  for (int o = 1; o < 64; o <<= 1) {  // full-wave butterfly (row = 1 wave)
    ssa += __shfl_xor(ssa, o, 64);
    ssb += __shfl_xor(ssb, o, 64);
    dt  += __shfl_xor(dt, o, 64);
  }
  const float ra = rsqrtf(ssa), rb = rsqrtf(ssb);
  if (j == 0) diag[row] = dt * ra * rb * 10.0f;
  const float sa = ra * ENC_SCALE, sb = rb * ENC_SCALE;

#define CVT_ST(av, bv, ofs)                                                  \
  {                                                                          \
    int pa_ = __builtin_amdgcn_cvt_pk_fp8_f32(av.x * sa, av.y * sa, 0, false); \
    pa_ = __builtin_amdgcn_cvt_pk_fp8_f32(av.z * sa, av.w * sa, pa_, true);  \
    int pb_ = __builtin_amdgcn_cvt_pk_fp8_f32(bv.x * sb, bv.y * sb, 0, false); \
    pb_ = __builtin_amdgcn_cvt_pk_fp8_f32(bv.z * sb, bv.w * sb, pb_, true);  \
    ldsA[r * 257 + j + (ofs)] = (unsigned int)pa_;                           \
    ldsB[r * 257 + j + (ofs)] = (unsigned int)pb_;                           \
  }
  CVT_ST(a0, b0, 0)
  CVT_ST(a1, b1, 64)
  CVT_ST(a2, b2, 128)
  CVT_ST(a3, b3, 192)
#undef CVT_ST
  __syncthreads();

  {
    const int s = t >> 5, c4 = t & 31;
    const int fl0 = c4 * 2, fl1 = fl0 + 1;
    const int i0 = (fl0 & 15) * 257 + s * 8 + (fl0 >> 4) * 2;
    const int i1 = (fl1 & 15) * 257 + s * 8 + (fl1 >> 4) * 2;
    uint4 va, vb;
    va.x = ldsA[i0]; va.y = ldsA[i0 + 1];
    va.z = ldsA[i1]; va.w = ldsA[i1 + 1];
    vb.x = ldsB[i0]; vb.y = ldsB[i0 + 1];
    vb.z = ldsB[i1]; vb.w = ldsB[i1 + 1];
    const size_t d = (size_t)s * 65536 + (size_t)til * 128 + c4 * 4;
    *(uint4*)(imn + d) = va;
    *(uint4*)(capn + d) = vb;
  }
}

// Kernel 2 [R13]: phase-split (T3) + setprio (T5) on the R12 ring-4 pipeline.
// Per K-tile, 2 phases (si=0/1). Each phase: {12 ds_read_b64 for this si ||
// 2 global_load_lds of tile kt+3} -> s_barrier -> lgkmcnt(0)+sched_barrier
// -> setprio(1) -> 32 MFMA -> setprio(0) -> s_barrier. ds_reads issue BEFORE
// the barrier and wait AFTER it: read latency hides under barrier sync and
// other waves' MFMA tails. vmcnt counted once per tile (ph1): FIFO leaves
// tiles kt+2,kt+3 (8 loads) in flight -> vmcnt(8), never drains to 0.
__global__ __launch_bounds__(512, 2) void gemm_lse_k(
    const unsigned char* __restrict__ A,   // swizzled imn
    const unsigned char* __restrict__ B,   // swizzled capn
    float* __restrict__ rowsum, float* __restrict__ colsum) {
  __shared__ unsigned char lds[4][32768];  // ring-4: [A 16KB | B 16KB] each
  const int t = threadIdx.x;
  const int w = t >> 6, l = t & 63;

  // XCD/L2 swizzle: contiguous 128-block chunk per XCD, row-tile fastest.
  const int bid = blockIdx.x + (blockIdx.y << 5);     // 0..1023
  const int nid = (bid & 7) * 128 + (bid >> 3);       // bijective (1024%8==0)
  const int rowT = ((nid >> 7) << 2) + (nid & 3);     // 0..31
  const int colT = (nid & 127) >> 2;                  // 0..31

  const size_t baseA = (size_t)rowT * 8192;  // 16 row-tiles x 512B per slab
  const size_t baseB = (size_t)colT * 8192;

  // staging roles: waves 0-3 fill the A half, waves 4-7 the B half.
  const unsigned char* __restrict__ P = (w < 4) ? A : B;
  const size_t pbase = (w < 4) ? baseA : baseB;
  const int wo = (w & 3) * 4096;
  const int lhalf = (w < 4) ? 0 : 16384;

// two GLD16 chunks (c0, c0+1) of tile data at global base ps into ring buf sb
#define STAGE2(ps, sb, c0)                                                   \
  {                                                                          \
    const int oA_ = wo + (c0) * 1024, oB_ = oA_ + 1024;                      \
    GLD16((ps) + (size_t)(oA_ >> 13) * SLAB + (oA_ & 8191) + l * 16,         \
          &lds[sb][lhalf + oA_]);                                            \
    GLD16((ps) + (size_t)(oB_ >> 13) * SLAB + (oB_ & 8191) + l * 16,         \
          &lds[sb][lhalf + oB_]);                                            \
  }

  const int wr = w >> 2, wc = w & 3;
  const int aoff = wr * 8 * 512 + l * 8;           // + si*8192 + m*512
  const int boff = 16384 + wc * 4 * 512 + l * 8;   // + si*8192 + n*512

  f32x4 acc[8][4];
#pragma unroll
  for (int m = 0; m < 8; ++m)
#pragma unroll
    for (int n = 0; n < 4; ++n) acc[m][n] = (f32x4){0.f, 0.f, 0.f, 0.f};

// fragment register loads for sub-slab si of ring buf cb (declares a_, b_)
#define READ_AB(cb, si)                                                      \
  long a_[8], b_[4];                                                         \
  {                                                                          \
    const unsigned char* Lc = &lds[cb][(si) * 8192];                         \
    _Pragma("unroll")                                                        \
    for (int m = 0; m < 8; ++m)                                              \
      a_[m] = *(const long*)(Lc + aoff + m * 512);                           \
    _Pragma("unroll")                                                        \
    for (int n = 0; n < 4; ++n)                                              \
      b_[n] = *(const long*)(Lc + boff + n * 512);                           \
  }

#define MFMA_ALL                                                             \
  _Pragma("unroll")                                                          \
  for (int m = 0; m < 8; ++m)                                                \
    _Pragma("unroll")                                                        \
    for (int n = 0; n < 4; ++n)                                              \
      acc[m][n] = __builtin_amdgcn_mfma_f32_16x16x32_fp8_fp8(                \
          a_[m], b_[n], acc[m][n], 0, 0, 0);

// barrier; wait own ds_reads (issued pre-barrier); pin; prio-MFMA; barrier
#define PH_COMPUTE                                                           \
  __builtin_amdgcn_s_barrier();                                              \
  asm volatile("s_waitcnt lgkmcnt(0)" ::: "memory");                         \
  __builtin_amdgcn_sched_barrier(0);                                         \
  __builtin_amdgcn_s_setprio(1);                                             \
  MFMA_ALL                                                                   \
  __builtin_amdgcn_s_setprio(0);                                             \
  __builtin_amdgcn_s_barrier();

  // prologue: stage tiles 0,1,2 (12 loads/wave); tile 0 landed -> vmcnt(8)
  {
    const unsigned char* p0 = P + pbase;
    STAGE2(p0, 0, 0) STAGE2(p0, 0, 2)
    const unsigned char* p1 = P + 2 * (size_t)SLAB + pbase;
    STAGE2(p1, 1, 0) STAGE2(p1, 1, 2)
    const unsigned char* p2 = P + 4 * (size_t)SLAB + pbase;
    STAGE2(p2, 2, 0) STAGE2(p2, 2, 2)
  }
  asm volatile("s_waitcnt vmcnt(8)" ::: "memory");
  __builtin_amdgcn_s_barrier();

  // main loop: per-wave vmem FIFO at iter start = {kt+1:4, kt+2:4}.
  // ph0 +2, ph1 +2 (tile kt+3 -> buf (kt-1)&3, freed at end of iter kt-1);
  // vmcnt(8) at ph1 retires tile kt+1's 4 loads before the barrier.
#pragma unroll 1
  for (int kt = 0; kt < 13; ++kt) {
    const int cb = kt & 3, sb = (kt + 3) & 3;
    const unsigned char* ps = P + (size_t)(kt + 3) * (2 * (size_t)SLAB) + pbase;
    {  // ph0
      READ_AB(cb, 0)
      STAGE2(ps, sb, 0)
      PH_COMPUTE
    }
    {  // ph1
      READ_AB(cb, 1)
      STAGE2(ps, sb, 2)
      asm volatile("s_waitcnt vmcnt(8)" ::: "memory");
      PH_COMPUTE
    }
  }
  // tail: tiles 13,14,15 in bufs 1,2,3 — drain 4 -> 0
  { READ_AB(1, 0) PH_COMPUTE }
  { READ_AB(1, 1) asm volatile("s_waitcnt vmcnt(4)" ::: "memory"); PH_COMPUTE }
  { READ_AB(2, 0) PH_COMPUTE }
  { READ_AB(2, 1) asm volatile("s_waitcnt vmcnt(0)" ::: "memory"); PH_COMPUTE }
  { READ_AB(3, 0) PH_COMPUTE }
  { READ_AB(3, 1) PH_COMPUTE }
#undef PH_COMPUTE
#undef MFMA_ALL
#undef READ_AB
#undef STAGE2

  // epilogue: exp (fixed-max LSE; |logit| <= 10, no overflow possible)
#pragma unroll
  for (int m = 0; m < 8; ++m)
#pragma unroll
    for (int n = 0; n < 4; ++n)
#pragma unroll
      for (int r = 0; r < 4; ++r)
        acc[m][n][r] = __expf(acc[m][n][r] * EPILOGUE_SCALE);

  // C/D layout: col = lane&15, row = (lane>>4)*4 + reg  [measured m89/m91]
  const int rowBase = rowT * 256 + (w >> 2) * 128;
  const int colBase = colT * 256 + (w & 3) * 64;
#pragma unroll
  for (int m = 0; m < 8; ++m)
#pragma unroll
    for (int r = 0; r < 4; ++r) {
      float v = 0.f;
#pragma unroll
      for (int n = 0; n < 4; ++n) v += acc[m][n][r];
      v += __shfl_xor(v, 1, 64);
      v += __shfl_xor(v, 2, 64);
      v += __shfl_xor(v, 4, 64);
      v += __shfl_xor(v, 8, 64);
      if ((l & 15) == 0)
        atomicAdd(&rowsum[rowBase + m * 16 + (l >> 4) * 4 + r], v);
    }
#pragma unroll
  for (int n = 0; n < 4; ++n) {
    float v = 0.f;
#pragma unroll
    for (int m = 0; m < 8; ++m)
      v += acc[m][n][0] + acc[m][n][1] + acc[m][n][2] + acc[m][n][3];
    v += __shfl_xor(v, 16, 64);
    v += __shfl_xor(v, 32, 64);
    if (l < 16)
      atomicAdd(&colsum[colBase + n * 16 + l], v);
  }
}

// Kernel 3: scalar reduce. [unchanged]
__global__ __launch_bounds__(256) void finalize_k(
    const float* __restrict__ rowsum, const float* __restrict__ colsum,
    const float* __restrict__ diag, float* __restrict__ out) {
  const int t = threadIdx.x;
  float lse = 0.f, dg = 0.f;
  for (int i = t; i < N_; i += 256) {
    lse += __logf(rowsum[i]) + __logf(colsum[i]);
    dg += diag[i];
  }
#pragma unroll
  for (int o = 32; o > 0; o >>= 1) {
    lse += __shfl_down(lse, o, 64);
    dg  += __shfl_down(dg, o, 64);
  }
  __shared__ float red[2][4];
  const int w = t >> 6, l = t & 63;
  if (l == 0) { red[0][w] = lse; red[1][w] = dg; }
  __syncthreads();
  if (t == 0) {
    lse = red[0][0] + red[0][1] + red[0][2] + red[0][3];
    dg  = red[1][0] + red[1][1] + red[1][2] + red[1][3];
    out[0] = 0.5f * lse / (float)N_ - dg / (float)N_;
  }
}

extern "C" void kernel_launch(void* const* d_in, const int* in_sizes, int n_in,
                              void* d_out, int out_size, void* d_ws, size_t ws_size,
                              hipStream_t stream) {
  const float* im = (const float*)d_in[0];
  const float* cap = (const float*)d_in[1];
  float* out = (float*)d_out;
  char* ws = (char*)d_ws;
  unsigned char* imn = (unsigned char*)ws;                 // 8 MB fp8 (swizzled)
  unsigned char* capn = imn + (size_t)N_ * D_;             // 8 MB fp8 (swizzled)
  float* rowsum = (float*)(ws + 2 * (size_t)N_ * D_);
  float* colsum = rowsum + N_;
  float* diag = colsum + N_;

  normalize_k<<<512, 1024, 0, stream>>>(im, cap, (unsigned int*)imn,
                                        (unsigned int*)capn, diag, rowsum);
  gemm_lse_k<<<dim3(32, 32), 512, 0, stream>>>(imn, capn, rowsum, colsum);
  finalize_k<<<1, 256, 0, stream>>>(rowsum, colsum, diag, out);
}

// Round 3
// 193.509 us; speedup vs baseline: 1.1426x; 1.1426x over previous
//
#include <hip/hip_runtime.h>
#include <stdint.h>

#define N_ 8192
#define D_ 1024
// logit = dot(imn,capn)/T; fp8 operands pre-scaled by 16 -> acc = 256*dot
#define EPILOGUE_SCALE (10.0f / 256.0f)
#define ENC_SCALE 16.0f
#define SLAB 262144  // bytes of one K-slab: 512 tiles x 512B fragments

typedef float f32x4 __attribute__((ext_vector_type(4)));

// async global->LDS, 16B per lane, LDS dest = wave-uniform base + lane*16
#define GLD16(gsrc, ldst)                                                    \
  __builtin_amdgcn_global_load_lds(                                          \
      (const __attribute__((address_space(1))) unsigned int*)(gsrc),         \
      (__attribute__((address_space(3))) unsigned int*)(ldst), 16, 0, 0)

// K=32 swizzled fragment layout (both operands), 8 MB each [R3/R5/R10-proven]:
//   byte addr = s*262144 + tile*512 + fl*8 + h*4
//   a wave's fragment (tile, s) is 64 lanes x 8B = 512B contiguous.

// Kernel 1 [unchanged]: normalize + fp8 encode + fragment-order stores.
__global__ __launch_bounds__(1024) void normalize_k(
    const float* __restrict__ im, const float* __restrict__ cap,
    unsigned int* __restrict__ imn, unsigned int* __restrict__ capn,
    float* __restrict__ diag, float* __restrict__ sums /* rowsum|colsum */) {
  __shared__ unsigned int ldsA[16 * 257];
  __shared__ unsigned int ldsB[16 * 257];
  const int til = blockIdx.x;
  const int t = threadIdx.x;
  if (til < 4) ((float4*)sums)[til * 1024 + t] = (float4){0.f, 0.f, 0.f, 0.f};

  const int r = t >> 6, j = t & 63;   // wave r = row r of tile; lane j
  const int row = til * 16 + r;
  const float4* __restrict__ aR = (const float4*)(im + (size_t)row * D_);
  const float4* __restrict__ bR = (const float4*)(cap + (size_t)row * D_);

  float4 a0 = aR[j], a1 = aR[j + 64], a2 = aR[j + 128], a3 = aR[j + 192];
  float4 b0 = bR[j], b1 = bR[j + 64], b2 = bR[j + 128], b3 = bR[j + 192];

  float ssa = a0.x * a0.x + a0.y * a0.y + a0.z * a0.z + a0.w * a0.w
            + a1.x * a1.x + a1.y * a1.y + a1.z * a1.z + a1.w * a1.w
            + a2.x * a2.x + a2.y * a2.y + a2.z * a2.z + a2.w * a2.w
            + a3.x * a3.x + a3.y * a3.y + a3.z * a3.z + a3.w * a3.w;
  float ssb = b0.x * b0.x + b0.y * b0.y + b0.z * b0.z + b0.w * b0.w
            + b1.x * b1.x + b1.y * b1.y + b1.z * b1.z + b1.w * b1.w
            + b2.x * b2.x + b2.y * b2.y + b2.z * b2.z + b2.w * b2.w
            + b3.x * b3.x + b3.y * b3.y + b3.z * b3.z + b3.w * b3.w;
  float dt  = a0.x * b0.x + a0.y * b0.y + a0.z * b0.z + a0.w * b0.w
            + a1.x * b1.x + a1.y * b1.y + a1.z * b1.z + a1.w * b1.w
            + a2.x * b2.x + a2.y * b2.y + a2.z * b2.z + a2.w * b2.w
            + a3.x * b3.x + a3.y * b3.y + a3.z * b3.z + a3.w * b3.w;
#pragma unroll
  for (int o = 1; o < 64; o <<= 1) {  // full-wave butterfly (row = 1 wave)
    ssa += __shfl_xor(ssa, o, 64);
    ssb += __shfl_xor(ssb, o, 64);
    dt  += __shfl_xor(dt, o, 64);
  }
  const float ra = rsqrtf(ssa), rb = rsqrtf(ssb);
  if (j == 0) diag[row] = dt * ra * rb * 10.0f;
  const float sa = ra * ENC_SCALE, sb = rb * ENC_SCALE;

#define CVT_ST(av, bv, ofs)                                                  \
  {                                                                          \
    int pa_ = __builtin_amdgcn_cvt_pk_fp8_f32(av.x * sa, av.y * sa, 0, false); \
    pa_ = __builtin_amdgcn_cvt_pk_fp8_f32(av.z * sa, av.w * sa, pa_, true);  \
    int pb_ = __builtin_amdgcn_cvt_pk_fp8_f32(bv.x * sb, bv.y * sb, 0, false); \
    pb_ = __builtin_amdgcn_cvt_pk_fp8_f32(bv.z * sb, bv.w * sb, pb_, true);  \
    ldsA[r * 257 + j + (ofs)] = (unsigned int)pa_;                           \
    ldsB[r * 257 + j + (ofs)] = (unsigned int)pb_;                           \
  }
  CVT_ST(a0, b0, 0)
  CVT_ST(a1, b1, 64)
  CVT_ST(a2, b2, 128)
  CVT_ST(a3, b3, 192)
#undef CVT_ST
  __syncthreads();

  {
    const int s = t >> 5, c4 = t & 31;
    const int fl0 = c4 * 2, fl1 = fl0 + 1;
    const int i0 = (fl0 & 15) * 257 + s * 8 + (fl0 >> 4) * 2;
    const int i1 = (fl1 & 15) * 257 + s * 8 + (fl1 >> 4) * 2;
    uint4 va, vb;
    va.x = ldsA[i0]; va.y = ldsA[i0 + 1];
    va.z = ldsA[i1]; va.w = ldsA[i1 + 1];
    vb.x = ldsB[i0]; vb.y = ldsB[i0 + 1];
    vb.z = ldsB[i1]; vb.w = ldsB[i1 + 1];
    const size_t d = (size_t)s * 65536 + (size_t)til * 128 + c4 * 4;
    *(uint4*)(imn + d) = va;
    *(uint4*)(capn + d) = vb;
  }
}

// Kernel 2 [R14]: occupancy rewrite. R2's phase-split/setprio REVERTED
// (regressed at 1 block/CU: lockstep waves, no role diversity). Root cause
// of the 45% MfmaUtil plateau: 128KB LDS + 220-reg waves = 1 block/CU, so
// every barrier/prologue/epilogue is a full-CU bubble. Now: 256x128 block
// tile, 8 waves of 64x64 (acc 64 regs, total ~115 -> 4 waves/SIMD class),
// ring-2 BK=64 (48KB LDS) -> 2 blocks/CU. Ring-2 stage-ahead-1 has the SAME
// buffer-reuse distance as R1's ring-4 stage-ahead-3; slack (1 compute iter
// ~2.4kcyc) still covers miss latency (~900cyc). Counted vmcnt(3), never 0
// in-loop. Cross-block TLP fills the bubbles.
__global__ __launch_bounds__(512, 4) void gemm_lse_k(
    const unsigned char* __restrict__ A,   // swizzled imn
    const unsigned char* __restrict__ B,   // swizzled capn
    float* __restrict__ rowsum, float* __restrict__ colsum) {
  __shared__ unsigned char lds[2][24576];  // ring-2: [A 16KB | B 8KB] each
  const int t = threadIdx.x;
  const int w = t >> 6, l = t & 63;

  // XCD/L2 swizzle: 256-block chunk per XCD; rowT in groups of 4, colT-major.
  const int bid = blockIdx.x + (blockIdx.y << 5);     // 0..2047
  const int nid = (bid & 7) * 256 + (bid >> 3);       // bijective (2048%8==0)
  const int rowT = ((nid >> 8) << 2) + (nid & 3);     // 0..31
  const int colT = (nid >> 2) & 63;                   // 0..63

  const size_t baseA = (size_t)rowT * 8192;  // 16 row-tiles x 512B per slab
  const size_t baseB = (size_t)colT * 4096;  //  8 col-tiles x 512B per slab

  // staging: 24KB/tile = 24 chunks of 1KB; wave w owns chunks 3w..3w+2
  // (mixed A/B by offset). Uniform 3 GLD16/wave/tile -> uniform vmcnt.
  // LDS map: [0,16K) = A [si:8K][tile:512]; [16K,24K) = B [si:4K][tile:512].
  const unsigned char* src[3];
  int ldsOff[3];
#pragma unroll
  for (int c = 0; c < 3; ++c) {
    const int o = w * 3072 + c * 1024;
    ldsOff[c] = o;
    if (o < 16384)
      src[c] = A + baseA + (size_t)(o >> 13) * SLAB + (o & 8191) + l * 16;
    else {
      const int ob = o - 16384;
      src[c] = B + baseB + (size_t)(ob >> 12) * SLAB + (ob & 4095) + l * 16;
    }
  }

#define STAGE(ktv, buf)                                                      \
  {                                                                          \
    const size_t kofs = (size_t)(ktv) * (2 * (size_t)SLAB);                  \
    GLD16(src[0] + kofs, &lds[buf][ldsOff[0]]);                              \
    GLD16(src[1] + kofs, &lds[buf][ldsOff[1]]);                              \
    GLD16(src[2] + kofs, &lds[buf][ldsOff[2]]);                              \
  }

  const int wr = w >> 1, wc = w & 1;         // 4M x 2N waves, 64x64 each
  const int aoff = wr * 2048 + l * 8;        // + si*8192 + m*512
  const int boff = wc * 2048 + l * 8;        // + 16384 + si*4096 + n*512

  f32x4 acc[4][4];
#pragma unroll
  for (int m = 0; m < 4; ++m)
#pragma unroll
    for (int n = 0; n < 4; ++n) acc[m][n] = (f32x4){0.f, 0.f, 0.f, 0.f};

#define COMPUTE(buf)                                                         \
  {                                                                          \
    const unsigned char* Lc = &lds[buf][0];                                  \
    _Pragma("unroll")                                                        \
    for (int si = 0; si < 2; ++si) {                                         \
      long a_[4], b_[4];                                                     \
      _Pragma("unroll")                                                      \
      for (int m = 0; m < 4; ++m)                                            \
        a_[m] = *(const long*)(Lc + si * 8192 + aoff + m * 512);             \
      _Pragma("unroll")                                                      \
      for (int n = 0; n < 4; ++n)                                            \
        b_[n] = *(const long*)(Lc + 16384 + si * 4096 + boff + n * 512);     \
      _Pragma("unroll")                                                      \
      for (int m = 0; m < 4; ++m)                                            \
        _Pragma("unroll")                                                    \
        for (int n = 0; n < 4; ++n)                                          \
          acc[m][n] = __builtin_amdgcn_mfma_f32_16x16x32_fp8_fp8(            \
              a_[m], b_[n], acc[m][n], 0, 0, 0);                             \
    }                                                                        \
  }

  // prologue: tile 0 in flight (3 loads/wave)
  STAGE(0, 0)

  // main loop: at iter kt, FIFO = {kt:3, kt+1:3} after STAGE; vmcnt(3)
  // retires tile kt, leaves kt+1 in flight across both barriers.
  // STAGE(kt+1) writes buf read at kt-1, freed at kt-1's end barrier.
#pragma unroll 1
  for (int kt = 0; kt < 15; ++kt) {
    STAGE(kt + 1, (kt + 1) & 1)
    asm volatile("s_waitcnt vmcnt(3)" ::: "memory");
    __builtin_amdgcn_s_barrier();
    COMPUTE(kt & 1)
    __builtin_amdgcn_s_barrier();
  }
  asm volatile("s_waitcnt vmcnt(0)" ::: "memory");
  __builtin_amdgcn_s_barrier();
  COMPUTE(1)
#undef COMPUTE
#undef STAGE

  // epilogue: exp (fixed-max LSE; |logit| <= 10, no overflow possible)
#pragma unroll
  for (int m = 0; m < 4; ++m)
#pragma unroll
    for (int n = 0; n < 4; ++n)
#pragma unroll
      for (int r = 0; r < 4; ++r)
        acc[m][n][r] = __expf(acc[m][n][r] * EPILOGUE_SCALE);

  // C/D layout: col = lane&15, row = (lane>>4)*4 + reg  [measured m89/m91]
  const int rowBase = rowT * 256 + wr * 64;
  const int colBase = colT * 128 + wc * 64;
#pragma unroll
  for (int m = 0; m < 4; ++m)
#pragma unroll
    for (int r = 0; r < 4; ++r) {
      float v = 0.f;
#pragma unroll
      for (int n = 0; n < 4; ++n) v += acc[m][n][r];
      v += __shfl_xor(v, 1, 64);
      v += __shfl_xor(v, 2, 64);
      v += __shfl_xor(v, 4, 64);
      v += __shfl_xor(v, 8, 64);
      if ((l & 15) == 0)
        atomicAdd(&rowsum[rowBase + m * 16 + (l >> 4) * 4 + r], v);
    }
#pragma unroll
  for (int n = 0; n < 4; ++n) {
    float v = 0.f;
#pragma unroll
    for (int m = 0; m < 4; ++m)
      v += acc[m][n][0] + acc[m][n][1] + acc[m][n][2] + acc[m][n][3];
    v += __shfl_xor(v, 16, 64);
    v += __shfl_xor(v, 32, 64);
    if (l < 16)
      atomicAdd(&colsum[colBase + n * 16 + l], v);
  }
}

// Kernel 3: scalar reduce. [unchanged]
__global__ __launch_bounds__(256) void finalize_k(
    const float* __restrict__ rowsum, const float* __restrict__ colsum,
    const float* __restrict__ diag, float* __restrict__ out) {
  const int t = threadIdx.x;
  float lse = 0.f, dg = 0.f;
  for (int i = t; i < N_; i += 256) {
    lse += __logf(rowsum[i]) + __logf(colsum[i]);
    dg += diag[i];
  }
#pragma unroll
  for (int o = 32; o > 0; o >>= 1) {
    lse += __shfl_down(lse, o, 64);
    dg  += __shfl_down(dg, o, 64);
  }
  __shared__ float red[2][4];
  const int w = t >> 6, l = t & 63;
  if (l == 0) { red[0][w] = lse; red[1][w] = dg; }
  __syncthreads();
  if (t == 0) {
    lse = red[0][0] + red[0][1] + red[0][2] + red[0][3];
    dg  = red[1][0] + red[1][1] + red[1][2] + red[1][3];
    out[0] = 0.5f * lse / (float)N_ - dg / (float)N_;
  }
}

extern "C" void kernel_launch(void* const* d_in, const int* in_sizes, int n_in,
                              void* d_out, int out_size, void* d_ws, size_t ws_size,
                              hipStream_t stream) {
  const float* im = (const float*)d_in[0];
  const float* cap = (const float*)d_in[1];
  float* out = (float*)d_out;
  char* ws = (char*)d_ws;
  unsigned char* imn = (unsigned char*)ws;                 // 8 MB fp8 (swizzled)
  unsigned char* capn = imn + (size_t)N_ * D_;             // 8 MB fp8 (swizzled)
  float* rowsum = (float*)(ws + 2 * (size_t)N_ * D_);
  float* colsum = rowsum + N_;
  float* diag = colsum + N_;

  normalize_k<<<512, 1024, 0, stream>>>(im, cap, (unsigned int*)imn,
                                        (unsigned int*)capn, diag, rowsum);
  gemm_lse_k<<<dim3(32, 64), 512, 0, stream>>>(imn, capn, rowsum, colsum);
  finalize_k<<<1, 256, 0, stream>>>(rowsum, colsum, diag, out);
}